// Round 10
// baseline (532.820 us; speedup 1.0000x reference)
//
#include <hip/hip_runtime.h>
#include <stdint.h>

// Problem constants
#define BQ 8
#define NXQ 512
#define WQ 16
#define DXQ 1536
#define DYQ 1024
#define DQ 768
#define HQ 12
#define PQ 8
// derived
#define MY 65536            // B*NX*W rows of y
#define BN_ROWS 4096        // B*NX

typedef __attribute__((ext_vector_type(8))) short short8;
typedef __attribute__((ext_vector_type(4))) float f32x4;
typedef unsigned short ushort_t;
typedef unsigned int uint_t;

__device__ __forceinline__ ushort_t f2bf(float f) {
  uint_t u = __float_as_uint(f);
  u += 0x7FFFu + ((u >> 16) & 1u);   // RNE
  return (ushort_t)(u >> 16);
}
__device__ __forceinline__ float bf2f(ushort_t h) {
  return __uint_as_float(((uint_t)h) << 16);
}
__device__ __forceinline__ void gload_lds16(const void* g, void* l) {
  __builtin_amdgcn_global_load_lds(
      (__attribute__((address_space(1))) unsigned int*)(g),
      (__attribute__((address_space(3))) unsigned int*)(l), 16, 0, 0);
}

// ---------------- K0: y->bf16, weight transposes, zeros, + q1 fold ------
// First 6144 threads also compute xw[b,c] = x[b,0,:]@Wx[:,c]+bx (full K,
// no atomics) — latency hidden under the HBM-bound streaming.
__global__ void k_conv(const float* __restrict__ y, const float* __restrict__ Wy,
                       const float* __restrict__ Wv, const float* __restrict__ Wo,
                       const float* __restrict__ x, const float* __restrict__ Wx,
                       const float* __restrict__ bx,
                       ushort_t* __restrict__ ybf, ushort_t* __restrict__ WyT,
                       ushort_t* __restrict__ WvT, ushort_t* __restrict__ WoT,
                       float* __restrict__ rowsq, float* __restrict__ oS12,
                       float* __restrict__ xw) {
  const int gstride = gridDim.x * blockDim.x;
  const int g0 = blockIdx.x * blockDim.x + threadIdx.x;
  // q1 fold: xw (8x768), one thread each
  if (g0 < BQ * DQ) {
    int b = g0 / DQ, c = g0 - b * DQ;
    const float* xr = x + (size_t)b * NXQ * DXQ;   // row 0 of batch b
    float acc = bx[c];
    for (int k = 0; k < DXQ; ++k) acc += xr[k] * Wx[(size_t)k * DQ + c];
    xw[g0] = acc;
  }
  // y fp32 -> bf16
  const int NY8 = MY * DYQ / 8;
  for (int i = g0; i < NY8; i += gstride) {
    const float4* s = (const float4*)(y + (size_t)i * 8);
    float4 f0 = s[0], f1 = s[1];
    short8 hv;
    hv[0] = (short)f2bf(f0.x); hv[1] = (short)f2bf(f0.y);
    hv[2] = (short)f2bf(f0.z); hv[3] = (short)f2bf(f0.w);
    hv[4] = (short)f2bf(f1.x); hv[5] = (short)f2bf(f1.y);
    hv[6] = (short)f2bf(f1.z); hv[7] = (short)f2bf(f1.w);
    *(short8*)(ybf + (size_t)i * 8) = hv;
  }
  // zeros
  for (int i = g0; i < MY; i += gstride) rowsq[i] = 0.f;
  for (int i = g0; i < 2 * BN_ROWS; i += gstride) oS12[i] = 0.f;
  // weight transposes (bf16)
  const int N1 = DQ * DYQ;
  const int N2 = DQ * DQ;
  const int total = N1 + 2 * N2;
  for (int i = g0; i < total; i += gstride) {
    if (i < N1) {
      int n = i / DYQ, k = i - n * DYQ;
      WyT[i] = f2bf(Wy[k * DQ + n]);
    } else if (i < N1 + N2) {
      int j = i - N1;
      int n = j / DQ, k = j - n * DQ;
      WvT[j] = f2bf(Wv[k * DQ + n]);
    } else {
      int j = i - N1 - N2;
      int n = j / DQ, k = j - n * DQ;
      WoT[j] = f2bf(Wo[k * DQ + n]);
    }
  }
}

// ---------------- q-chain ------------------------------------------------
__global__ __launch_bounds__(128) void k_q2(const float* __restrict__ xw,
                                            const float* __restrict__ Wq,
                                            const float* __restrict__ bq,
                                            float* __restrict__ qv) {
  const int b = blockIdx.x, c = blockIdx.y * 128 + threadIdx.x;
  const float* xr = xw + b * DQ;
  float acc = 0.f, ss = 0.f;
  for (int k = 0; k < DQ; ++k) {
    float v = xr[k];
    acc += v * Wq[(size_t)k * DQ + c];
    ss += v * v;
  }
  const float inv = 1.0f / (sqrtf(ss) + 1e-6f);
  qv[b * DQ + c] = (acc * inv + bq[c]) * 0.125f;
}

__global__ void k_q3(const float* __restrict__ Wk, const float* __restrict__ bk,
                     const float* __restrict__ qv, float* __restrict__ qk,
                     float* __restrict__ cQ) {
  const int bh = blockIdx.x;
  const int b = bh / HQ, h = bh - b * HQ;
  const int tid = threadIdx.x;
  const float* q = qv + b * DQ + h * 64;
#pragma unroll
  for (int j = 0; j < 3; ++j) {
    int dd = tid + j * 256;
    float acc = 0.f;
    for (int j2 = 0; j2 < 64; ++j2) acc += Wk[(size_t)dd * DQ + h * 64 + j2] * q[j2];
    qk[(size_t)bh * DQ + dd] = acc;
  }
  if (tid == 0) {
    float acc = 0.f;
    for (int j2 = 0; j2 < 64; ++j2) acc += q[j2] * bk[h * 64 + j2];
    cQ[bh] = acc;
  }
}

// ---------------- K1: z = ybf @ WyT^T + by (bf16), rowsq += ssq ---------
// BM=256, BN=256, BK=64, 8 waves (2Mx4N, wave tile 128x64).
// Ring of 4 x 32KB quarter-slots, lead-3 staging, counted vmcnt(8).
// Swizzle f(r) = (r>>1)&3 -> ds_read_b128 hits all 8 bank-groups (2-way,
// free); old (r&3) was 4-way-conflicted.
__global__ __launch_bounds__(512, 1) void k_gemm_yp(const ushort_t* __restrict__ ybf,
                                                    const ushort_t* __restrict__ WyT,
                                                    const float* __restrict__ by,
                                                    ushort_t* __restrict__ z,
                                                    float* __restrict__ rowsqg) {
  __shared__ __align__(16) char smem[131072 + 1024];
  float* rowsq_l = (float*)(smem + 131072);
  const int tid = threadIdx.x, lane = tid & 63, wv = tid >> 6;
  const int wvM = wv >> 2, wvN = wv & 3;
  const int g = blockIdx.x;
  const int m = (g / 24) * 8 + (g & 7);
  const int n = (g >> 3) % 3;
  const int mBase = m * 256, nBase = n * 256;
  if (tid < 256) rowsq_l[tid] = 0.f;

  // staging sources: source chunk pre-swizzled with f(row) = ((lane>>3)&3)
  const int sr = lane >> 2;
  const int sc = (lane & 3) ^ ((lane >> 3) & 3);
  const ushort_t* aQ[2]; const ushort_t* bQ[2];
  int qDst[2];
#pragma unroll
  for (int j = 0; j < 2; ++j) {
    int r = wv * 32 + j * 16 + sr;
    aQ[j] = ybf + (size_t)(mBase + r) * DYQ + sc * 8;
    bQ[j] = WyT + (size_t)(nBase + r) * DYQ + sc * 8;
    qDst[j] = (wv * 32 + j * 16) * 64;
  }
  // fragment read offsets; phys chunk = q ^ ((r>>1)&3), r-base mult of 16
  const int q = lane >> 4;
  const int fsw = ((lane & 15) >> 1) & 3;
  int aFr[8], bFr[4];
#pragma unroll
  for (int mf = 0; mf < 8; ++mf) {
    int r = wvM * 128 + mf * 16 + (lane & 15);
    aFr[mf] = r * 64 + ((q ^ fsw) << 4);
  }
#pragma unroll
  for (int nf = 0; nf < 4; ++nf) {
    int r = wvN * 64 + nf * 16 + (lane & 15);
    bFr[nf] = 16384 + r * 64 + ((q ^ fsw) << 4);
  }

#define YP_STAGE(pp)                                                           \
  {                                                                            \
    char* db = smem + ((pp) & 3) * 32768;                                      \
    const int koff = ((pp) >> 1) * 64 + ((pp) & 1) * 32;                       \
    _Pragma("unroll") for (int j = 0; j < 2; ++j)                              \
        gload_lds16(aQ[j] + koff, db + qDst[j]);                               \
    _Pragma("unroll") for (int j = 0; j < 2; ++j)                              \
        gload_lds16(bQ[j] + koff, db + 16384 + qDst[j]);                       \
  }

  f32x4 acc[8][4] = {};
  YP_STAGE(0);
  YP_STAGE(1);
  YP_STAGE(2);
  asm volatile("s_waitcnt vmcnt(8)" ::: "memory");   // stage(0) landed
  __builtin_amdgcn_s_barrier();
  __builtin_amdgcn_sched_barrier(0);

  for (int t = 0; t < 16; ++t) {
#pragma unroll
    for (int ks = 0; ks < 2; ++ks) {
      const int p = 2 * t + ks;
      const char* cb = smem + (p & 3) * 32768;
      short8 af[8], bf[4];
#pragma unroll
      for (int mf = 0; mf < 8; ++mf) af[mf] = *(const short8*)(cb + aFr[mf]);
#pragma unroll
      for (int nf = 0; nf < 4; ++nf) bf[nf] = *(const short8*)(cb + bFr[nf]);
      if (p <= 28) YP_STAGE(p + 3);
      asm volatile("s_waitcnt lgkmcnt(0)" ::: "memory");
      __builtin_amdgcn_sched_barrier(0);
      __builtin_amdgcn_s_setprio(1);
#pragma unroll
      for (int nf = 0; nf < 4; ++nf)
#pragma unroll
        for (int mf = 0; mf < 8; ++mf)
          acc[mf][nf] = __builtin_amdgcn_mfma_f32_16x16x32_bf16(af[mf], bf[nf],
                                                                acc[mf][nf], 0, 0, 0);
      __builtin_amdgcn_s_setprio(0);
      __builtin_amdgcn_sched_barrier(0);
      if (p <= 28) {
        asm volatile("s_waitcnt vmcnt(8)" ::: "memory");   // stage(p+1) landed
      } else if (p == 29) {
        asm volatile("s_waitcnt vmcnt(4)" ::: "memory");
      } else {
        asm volatile("s_waitcnt vmcnt(0)" ::: "memory");
      }
      __builtin_amdgcn_s_barrier();
      __builtin_amdgcn_sched_barrier(0);
    }
  }
  __syncthreads();

  // ---- epilogue: +bias, z tile (256x256) -> LDS, row ssq partials ----
  float byv[4];
#pragma unroll
  for (int nf = 0; nf < 4; ++nf) byv[nf] = by[nBase + wvN * 64 + nf * 16 + (lane & 15)];
#pragma unroll
  for (int mf = 0; mf < 8; ++mf) {
#pragma unroll
    for (int rr = 0; rr < 4; ++rr) {
      int row_l = wvM * 128 + mf * 16 + (lane >> 4) * 4 + rr;
      float ss = 0.f;
#pragma unroll
      for (int nf = 0; nf < 4; ++nf) {
        float zv = acc[mf][nf][rr] + byv[nf];
        ss += zv * zv;
        int col_l = wvN * 64 + nf * 16 + (lane & 15);
        *(ushort_t*)(smem + row_l * 512 + col_l * 2) = f2bf(zv);
      }
#pragma unroll
      for (int o = 1; o < 16; o <<= 1) ss += __shfl_xor(ss, o, 64);
      if ((lane & 15) == 0) atomicAdd(&rowsq_l[row_l], ss);
    }
  }
  __syncthreads();
  if (tid < 256) atomicAdd(&rowsqg[mBase + tid], rowsq_l[tid]);
#pragma unroll
  for (int it = 0; it < 16; ++it) {
    int row = it * 16 + (tid >> 5);
    int ch = tid & 31;
    uint4 v = *(const uint4*)(smem + row * 512 + ch * 16);
    *(uint4*)(z + (size_t)(mBase + row) * DQ + nBase + ch * 8) = v;
  }
}

// ---------------- K2: windowed attention -> p[b,n,h,:] ------------------
__global__ __launch_bounds__(256) void k_attn(const ushort_t* __restrict__ z,
                                              const float* __restrict__ rowsqg,
                                              const float* __restrict__ qk,
                                              const float* __restrict__ cQ,
                                              ushort_t* __restrict__ p) {
  __shared__ __align__(16) char smem[16 * 1552 + 192 * 4 * 2 + 64];
  float* s_l = (float*)(smem + 16 * 1552);
  float* a_l = s_l + 192;
  float* inv_l = a_l + 192;
  const int bn = blockIdx.x, b = bn >> 9;
  const int tid = threadIdx.x;
  if (tid < 16) inv_l[tid] = 1.0f / (sqrtf(rowsqg[bn * 16 + tid]) + 1e-6f);
  for (int j = tid; j < 16 * 96; j += 256) {
    int w = j / 96, ch = j - w * 96;
    *(short8*)(smem + w * 1552 + ch * 16) =
        *(const short8*)(z + ((size_t)bn * 16 + w) * DQ + ch * 8);
  }
  __syncthreads();
  if (tid < 192) {  // (h,w): s = (z_w . qk~) * inv_w + cQ
    int h = tid >> 4, w = tid & 15;
    const float4* qkp = (const float4*)(qk + (size_t)(b * HQ + h) * DQ);
    float acc = 0.f;
    const char* yrow = smem + w * 1552;
    for (int dc = 0; dc < 192; ++dc) {
      float4 q4 = qkp[dc];
      uint2 hh = *(const uint2*)(yrow + dc * 8);
      acc += q4.x * bf2f((ushort_t)(hh.x & 0xffff));
      acc += q4.y * bf2f((ushort_t)(hh.x >> 16));
      acc += q4.z * bf2f((ushort_t)(hh.y & 0xffff));
      acc += q4.w * bf2f((ushort_t)(hh.y >> 16));
    }
    s_l[tid] = acc * inv_l[w] + cQ[b * HQ + h];
  }
  __syncthreads();
  if (tid < 12) {  // softmax over w; fold inv_w into weights
    float mx = -1e30f;
#pragma unroll
    for (int w = 0; w < 16; ++w) mx = fmaxf(mx, s_l[tid * 16 + w]);
    float sm = 0.f, ev[16];
#pragma unroll
    for (int w = 0; w < 16; ++w) {
      ev[w] = __expf(s_l[tid * 16 + w] - mx);
      sm += ev[w];
    }
    float rden = 1.0f / sm;
#pragma unroll
    for (int w = 0; w < 16; ++w) a_l[tid * 16 + w] = ev[w] * rden * inv_l[w];
  }
  __syncthreads();
  float zr[16][3];
#pragma unroll
  for (int w = 0; w < 16; ++w)
#pragma unroll
    for (int i = 0; i < 3; ++i)
      zr[w][i] = bf2f(*(const ushort_t*)(smem + w * 1552 + (tid + i * 256) * 2));
  for (int h = 0; h < HQ; ++h) {
    float acc0 = 0.f, acc1 = 0.f, acc2 = 0.f;
#pragma unroll
    for (int w = 0; w < 16; ++w) {
      float aw = a_l[h * 16 + w];
      acc0 += aw * zr[w][0];
      acc1 += aw * zr[w][1];
      acc2 += aw * zr[w][2];
    }
    size_t base = ((size_t)bn * HQ + h) * DQ + tid;
    p[base] = f2bf(acc0);
    p[base + 256] = f2bf(acc1);
    p[base + 512] = f2bf(acc2);
  }
}

// ---------------- K3: ctx[:, h*64:(h+1)*64] = p_h @ Wv_h + bv -----------
#define PV_TSZ 24576         // A 16KB + B 8KB
__global__ __launch_bounds__(256) void k_gemm_pv(const ushort_t* __restrict__ p,
                                                 const ushort_t* __restrict__ WvT,
                                                 const float* __restrict__ bv,
                                                 ushort_t* __restrict__ ctx) {
  __shared__ __align__(16) char smem[3 * PV_TSZ];
  const int tid = threadIdx.x, lane = tid & 63, wv = tid >> 6;
  const int wvM = wv >> 1, wvN = wv & 1;
  const int mBase = blockIdx.x * 128, h = blockIdx.y;
  const int l8 = lane >> 3;
  const int c8 = (lane & 7) ^ (l8 & 7);
  const ushort_t* aSrc[4]; const ushort_t* bSrc[2];
  int aDst[4], bDst[2];
#pragma unroll
  for (int j = 0; j < 4; ++j) {
    int r = wv * 32 + j * 8 + l8;
    aSrc[j] = p + ((size_t)(mBase + r) * HQ + h) * DQ + c8 * 8;
    aDst[j] = (wv * 32 + j * 8) * 128;
  }
#pragma unroll
  for (int j = 0; j < 2; ++j) {
    int r = wv * 16 + j * 8 + l8;
    bSrc[j] = WvT + (size_t)(h * 64 + r) * DQ + c8 * 8;
    bDst[j] = 16384 + (wv * 16 + j * 8) * 128;
  }
  const int q = lane >> 4;
  int aRowB[4], aSw[4], bRowB[2], bSw[2];
#pragma unroll
  for (int mf = 0; mf < 4; ++mf) {
    int r = wvM * 64 + mf * 16 + (lane & 15);
    aRowB[mf] = r * 128; aSw[mf] = r & 7;
  }
#pragma unroll
  for (int nf = 0; nf < 2; ++nf) {
    int r = wvN * 32 + nf * 16 + (lane & 15);
    bRowB[nf] = 16384 + r * 128; bSw[nf] = r & 7;
  }
#define PV_STAGE(dbuf, t)                                                      \
  {                                                                            \
    char* db = smem + (dbuf) * PV_TSZ;                                         \
    _Pragma("unroll") for (int j = 0; j < 4; ++j)                              \
        gload_lds16(aSrc[j] + (t) * 64, db + aDst[j]);                         \
    _Pragma("unroll") for (int j = 0; j < 2; ++j)                              \
        gload_lds16(bSrc[j] + (t) * 64, db + bDst[j]);                         \
  }
  f32x4 acc[4][2] = {};
  PV_STAGE(0, 0);
  PV_STAGE(1, 1);
  int bR = 0, bS = 2;
  for (int t = 0; t < 12; ++t) {
    if (t < 11) {
      asm volatile("s_waitcnt vmcnt(6)" ::: "memory");
    } else {
      asm volatile("s_waitcnt vmcnt(0)" ::: "memory");
    }
    __builtin_amdgcn_s_barrier();
    __builtin_amdgcn_sched_barrier(0);
    if (t + 2 < 12) PV_STAGE(bS, t + 2);
    const char* cur = smem + bR * PV_TSZ;
#pragma unroll
    for (int ks = 0; ks < 2; ++ks) {
      short8 af[4], bf[2];
#pragma unroll
      for (int mf = 0; mf < 4; ++mf)
        af[mf] = *(const short8*)(cur + aRowB[mf] + (((ks * 4 + q) ^ aSw[mf]) << 4));
#pragma unroll
      for (int nf = 0; nf < 2; ++nf)
        bf[nf] = *(const short8*)(cur + bRowB[nf] + (((ks * 4 + q) ^ bSw[nf]) << 4));
#pragma unroll
      for (int nf = 0; nf < 2; ++nf)
#pragma unroll
        for (int mf = 0; mf < 4; ++mf)
          acc[mf][nf] = __builtin_amdgcn_mfma_f32_16x16x32_bf16(af[mf], bf[nf],
                                                                acc[mf][nf], 0, 0, 0);
    }
    bR = (bR == 2) ? 0 : bR + 1;
    bS = (bS == 2) ? 0 : bS + 1;
  }
#pragma unroll
  for (int nf = 0; nf < 2; ++nf) {
    int col = h * 64 + wvN * 32 + nf * 16 + (lane & 15);
    float bvv = bv[col];
#pragma unroll
    for (int mf = 0; mf < 4; ++mf)
#pragma unroll
      for (int rr = 0; rr < 4; ++rr) {
        int row = mBase + wvM * 64 + mf * 16 + (lane >> 4) * 4 + rr;
        ctx[(size_t)row * DQ + col] = f2bf(acc[mf][nf][rr] + bvv);
      }
  }
}

// ---------------- K4: o = ctx @ Wo + bo (fp32) + row s1/s2 atomics ------
__global__ __launch_bounds__(256) void k_gemm_o(const ushort_t* __restrict__ ctx,
                                                const ushort_t* __restrict__ WoT,
                                                const float* __restrict__ bo,
                                                float* __restrict__ o,
                                                float* __restrict__ oS12) {
  __shared__ __align__(16) char smem[3 * PV_TSZ];
  const int tid = threadIdx.x, lane = tid & 63, wv = tid >> 6;
  const int wvM = wv >> 1, wvN = wv & 1;
  const int mBase = blockIdx.x * 128, nBase = blockIdx.y * 64;
  const int l8 = lane >> 3;
  const int c8 = (lane & 7) ^ (l8 & 7);
  const ushort_t* aSrc[4]; const ushort_t* bSrc[2];
  int aDst[4], bDst[2];
#pragma unroll
  for (int j = 0; j < 4; ++j) {
    int r = wv * 32 + j * 8 + l8;
    aSrc[j] = ctx + (size_t)(mBase + r) * DQ + c8 * 8;
    aDst[j] = (wv * 32 + j * 8) * 128;
  }
#pragma unroll
  for (int j = 0; j < 2; ++j) {
    int r = wv * 16 + j * 8 + l8;
    bSrc[j] = WoT + (size_t)(nBase + r) * DQ + c8 * 8;
    bDst[j] = 16384 + (wv * 16 + j * 8) * 128;
  }
  const int q = lane >> 4;
  int aRowB[4], aSw[4], bRowB[2], bSw[2];
#pragma unroll
  for (int mf = 0; mf < 4; ++mf) {
    int r = wvM * 64 + mf * 16 + (lane & 15);
    aRowB[mf] = r * 128; aSw[mf] = r & 7;
  }
#pragma unroll
  for (int nf = 0; nf < 2; ++nf) {
    int r = wvN * 32 + nf * 16 + (lane & 15);
    bRowB[nf] = 16384 + r * 128; bSw[nf] = r & 7;
  }
  f32x4 acc[4][2] = {};
#define O_STAGE(dbuf, t)                                                       \
  {                                                                            \
    char* db = smem + (dbuf) * PV_TSZ;                                         \
    _Pragma("unroll") for (int j = 0; j < 4; ++j)                              \
        gload_lds16(aSrc[j] + (t) * 64, db + aDst[j]);                         \
    _Pragma("unroll") for (int j = 0; j < 2; ++j)                              \
        gload_lds16(bSrc[j] + (t) * 64, db + bDst[j]);                         \
  }
  O_STAGE(0, 0);
  O_STAGE(1, 1);
  int bR = 0, bS = 2;
  for (int t = 0; t < 12; ++t) {
    if (t < 11) {
      asm volatile("s_waitcnt vmcnt(6)" ::: "memory");
    } else {
      asm volatile("s_waitcnt vmcnt(0)" ::: "memory");
    }
    __builtin_amdgcn_s_barrier();
    __builtin_amdgcn_sched_barrier(0);
    if (t + 2 < 12) O_STAGE(bS, t + 2);
    const char* cur = smem + bR * PV_TSZ;
#pragma unroll
    for (int ks = 0; ks < 2; ++ks) {
      short8 af[4], bf[2];
#pragma unroll
      for (int mf = 0; mf < 4; ++mf)
        af[mf] = *(const short8*)(cur + aRowB[mf] + (((ks * 4 + q) ^ aSw[mf]) << 4));
#pragma unroll
      for (int nf = 0; nf < 2; ++nf)
        bf[nf] = *(const short8*)(cur + bRowB[nf] + (((ks * 4 + q) ^ bSw[nf]) << 4));
#pragma unroll
      for (int nf = 0; nf < 2; ++nf)
#pragma unroll
        for (int mf = 0; mf < 4; ++mf)
          acc[mf][nf] = __builtin_amdgcn_mfma_f32_16x16x32_bf16(af[mf], bf[nf],
                                                                acc[mf][nf], 0, 0, 0);
    }
    bR = (bR == 2) ? 0 : bR + 1;
    bS = (bS == 2) ? 0 : bS + 1;
  }
  float bo0 = bo[nBase + wvN * 32 + (lane & 15)];
  float bo1 = bo[nBase + wvN * 32 + 16 + (lane & 15)];
#pragma unroll
  for (int mf = 0; mf < 4; ++mf)
#pragma unroll
    for (int rr = 0; rr < 4; ++rr) {
      int row = mBase + wvM * 64 + mf * 16 + (lane >> 4) * 4 + rr;
      float z0 = acc[mf][0][rr] + bo0;
      float z1 = acc[mf][1][rr] + bo1;
      o[(size_t)row * DQ + nBase + wvN * 32 + (lane & 15)] = z0;
      o[(size_t)row * DQ + nBase + wvN * 32 + 16 + (lane & 15)] = z1;
      float s1 = z0 + z1, s2 = z0 * z0 + z1 * z1;
#pragma unroll
      for (int ofs = 1; ofs < 16; ofs <<= 1) {
        s1 += __shfl_xor(s1, ofs, 64);
        s2 += __shfl_xor(s2, ofs, 64);
      }
      if ((lane & 15) == 0) {
        atomicAdd(&oS12[row], s1);
        atomicAdd(&oS12[BN_ROWS + row], s2);
      }
    }
}

// K5: LayerNorm finalize + prompt broadcast -> out
__global__ __launch_bounds__(256) void k_out(const float* __restrict__ o,
                                             const float* __restrict__ oS12,
                                             const float* __restrict__ ln_g,
                                             const float* __restrict__ ln_b,
                                             const float* __restrict__ prompt,
                                             float* __restrict__ out) {
  const int row = blockIdx.x;
  const int tid = threadIdx.x;
  float mu = oS12[row] * (1.0f / DQ);
  float va = oS12[BN_ROWS + row] * (1.0f / DQ) - mu * mu;
  float rstd = rsqrtf(va + 1e-6f);
  int b = row >> 9, n = row & 511;
  size_t obase = ((size_t)b * (NXQ * (PQ + 1)) + (size_t)n * (PQ + 1)) * DQ;
#pragma unroll
  for (int j = 0; j < 3; ++j) {
    int col = tid + j * 256;
    out[obase + col] = (o[(size_t)row * DQ + col] - mu) * rstd * ln_g[col] + ln_b[col];
  }
#pragma unroll
  for (int pi = 0; pi < PQ; ++pi)
#pragma unroll
    for (int j = 0; j < 3; ++j) {
      int col = tid + j * 256;
      out[obase + (size_t)(1 + pi) * DQ + col] = prompt[pi * DQ + col];
    }
}

extern "C" void kernel_launch(void* const* d_in, const int* in_sizes, int n_in,
                              void* d_out, int out_size, void* d_ws, size_t ws_size,
                              hipStream_t stream) {
  (void)in_sizes; (void)n_in; (void)out_size; (void)ws_size;
  const float* x    = (const float*)d_in[0];
  const float* y    = (const float*)d_in[1];
  const float* Wx   = (const float*)d_in[2];
  const float* bx   = (const float*)d_in[3];
  const float* Wy   = (const float*)d_in[4];
  const float* by   = (const float*)d_in[5];
  const float* prom = (const float*)d_in[6];
  const float* Wq   = (const float*)d_in[7];
  const float* bq   = (const float*)d_in[8];
  const float* Wk   = (const float*)d_in[9];
  const float* bk   = (const float*)d_in[10];
  const float* Wv   = (const float*)d_in[11];
  const float* bv   = (const float*)d_in[12];
  const float* Wo   = (const float*)d_in[13];
  const float* bo   = (const float*)d_in[14];
  const float* lng  = (const float*)d_in[15];
  const float* lnb  = (const float*)d_in[16];
  float* out = (float*)d_out;
  char* ws = (char*)d_ws;

  // ---- workspace layout (aliased) ----
  size_t oWyT = 0;
  size_t oWvT = oWyT + (size_t)DQ * DYQ * 2;
  size_t oWoT = oWvT + (size_t)DQ * DQ * 2;
  size_t oXw  = oWoT + (size_t)DQ * DQ * 2;
  size_t oQ   = oXw + (size_t)BQ * DQ * 4 + 256;
  size_t oQK  = oQ + (size_t)BQ * DQ * 4;
  size_t oC   = oQK + (size_t)BQ * HQ * DQ * 4;
  size_t oRq  = oC + 1024;
  size_t oS   = oRq + (size_t)MY * 4;
  size_t oYbf = oS + (size_t)2 * BN_ROWS * 4;
  size_t oZ   = oYbf + (size_t)MY * DYQ * 2;
  size_t oP   = oYbf;                                 // alias (ybf dead)
  size_t oCtx = oYbf + (size_t)BN_ROWS * HQ * DQ * 2;
  size_t oO   = oZ;                                   // alias (z dead)

  ushort_t* WyT = (ushort_t*)(ws + oWyT);
  ushort_t* WvT = (ushort_t*)(ws + oWvT);
  ushort_t* WoT = (ushort_t*)(ws + oWoT);
  float* xw  = (float*)(ws + oXw);
  float* qv  = (float*)(ws + oQ);
  float* qk  = (float*)(ws + oQK);
  float* cQ  = (float*)(ws + oC);
  float* rowsq = (float*)(ws + oRq);
  float* oS12  = (float*)(ws + oS);
  ushort_t* ybf  = (ushort_t*)(ws + oYbf);
  ushort_t* zbuf = (ushort_t*)(ws + oZ);
  ushort_t* p    = (ushort_t*)(ws + oP);
  ushort_t* ctx  = (ushort_t*)(ws + oCtx);
  float* obuf    = (float*)(ws + oO);

  k_conv<<<dim3(4096), dim3(256), 0, stream>>>(y, Wy, Wv, Wo, x, Wx, bx,
                                               ybf, WyT, WvT, WoT, rowsq, oS12, xw);
  k_q2<<<dim3(BQ, 6), dim3(128), 0, stream>>>(xw, Wq, bq, qv);
  k_q3<<<dim3(BQ * HQ), dim3(256), 0, stream>>>(Wk, bk, qv, qk, cQ);
  k_gemm_yp<<<dim3(768), dim3(512), 0, stream>>>(ybf, WyT, by, zbuf, rowsq);
  k_attn<<<dim3(BN_ROWS), dim3(256), 0, stream>>>(zbuf, rowsq, qk, cQ, p);
  k_gemm_pv<<<dim3(BN_ROWS / 128, HQ), dim3(256), 0, stream>>>(p, WvT, bv, ctx);
  k_gemm_o<<<dim3(BN_ROWS / 128, DQ / 64), dim3(256), 0, stream>>>(ctx, WoT, bo, obuf, oS12);
  k_out<<<dim3(BN_ROWS), dim3(256), 0, stream>>>(obuf, oS12, lng, lnb, prom, out);
}

// Round 11
// 445.491 us; speedup vs baseline: 1.1960x; 1.1960x over previous
//
#include <hip/hip_runtime.h>
#include <stdint.h>

// Problem constants
#define BQ 8
#define NXQ 512
#define WQ 16
#define DXQ 1536
#define DYQ 1024
#define DQ 768
#define HQ 12
#define PQ 8
// derived
#define MY 65536            // B*NX*W rows of y
#define BN_ROWS 4096        // B*NX

typedef __attribute__((ext_vector_type(8))) short short8;
typedef __attribute__((ext_vector_type(4))) float f32x4;
typedef unsigned short ushort_t;
typedef unsigned int uint_t;

__device__ __forceinline__ ushort_t f2bf(float f) {
  uint_t u = __float_as_uint(f);
  u += 0x7FFFu + ((u >> 16) & 1u);   // RNE
  return (ushort_t)(u >> 16);
}
__device__ __forceinline__ float bf2f(ushort_t h) {
  return __uint_as_float(((uint_t)h) << 16);
}
__device__ __forceinline__ void gload_lds16(const void* g, void* l) {
  __builtin_amdgcn_global_load_lds(
      (__attribute__((address_space(1))) unsigned int*)(g),
      (__attribute__((address_space(3))) unsigned int*)(l), 16, 0, 0);
}

// ---------------- K0: y->bf16, weight transposes, zero accumulators -----
__global__ void k_conv(const float* __restrict__ y, const float* __restrict__ Wy,
                       const float* __restrict__ Wv, const float* __restrict__ Wo,
                       ushort_t* __restrict__ ybf, ushort_t* __restrict__ WyT,
                       ushort_t* __restrict__ WvT, ushort_t* __restrict__ WoT,
                       float* __restrict__ rowsq, float* __restrict__ oS12,
                       float* __restrict__ xw) {
  const int gstride = gridDim.x * blockDim.x;
  const int g0 = blockIdx.x * blockDim.x + threadIdx.x;
  // y fp32 -> bf16
  const int NY8 = MY * DYQ / 8;
  for (int i = g0; i < NY8; i += gstride) {
    const float4* s = (const float4*)(y + (size_t)i * 8);
    float4 f0 = s[0], f1 = s[1];
    short8 hv;
    hv[0] = (short)f2bf(f0.x); hv[1] = (short)f2bf(f0.y);
    hv[2] = (short)f2bf(f0.z); hv[3] = (short)f2bf(f0.w);
    hv[4] = (short)f2bf(f1.x); hv[5] = (short)f2bf(f1.y);
    hv[6] = (short)f2bf(f1.z); hv[7] = (short)f2bf(f1.w);
    *(short8*)(ybf + (size_t)i * 8) = hv;
  }
  // zeros
  for (int i = g0; i < MY; i += gstride) rowsq[i] = 0.f;
  for (int i = g0; i < 2 * BN_ROWS; i += gstride) oS12[i] = 0.f;
  for (int i = g0; i < BQ * DQ; i += gstride) xw[i] = 0.f;
  // weight transposes (bf16)
  const int N1 = DQ * DYQ;
  const int N2 = DQ * DQ;
  const int total = N1 + 2 * N2;
  for (int i = g0; i < total; i += gstride) {
    if (i < N1) {
      int n = i / DYQ, k = i - n * DYQ;
      WyT[i] = f2bf(Wy[k * DQ + n]);
    } else if (i < N1 + N2) {
      int j = i - N1;
      int n = j / DQ, k = j - n * DQ;
      WvT[j] = f2bf(Wv[k * DQ + n]);
    } else {
      int j = i - N1 - N2;
      int n = j / DQ, k = j - n * DQ;
      WoT[j] = f2bf(Wo[k * DQ + n]);
    }
  }
}

// ---------------- q-chain ------------------------------------------------
__global__ __launch_bounds__(128) void k_q1(const float* __restrict__ x,
                                            const float* __restrict__ Wx,
                                            const float* __restrict__ bx,
                                            float* __restrict__ xw) {
  const int b = blockIdx.x, c = blockIdx.y * 128 + threadIdx.x;
  const int kc = blockIdx.z;
  const float* xr = x + (size_t)b * NXQ * DXQ + kc * 192;
  const float* wp = Wx + (size_t)kc * 192 * DQ + c;
  float acc = (kc == 0) ? bx[c] : 0.f;
  for (int k = 0; k < 192; ++k) acc += xr[k] * wp[(size_t)k * DQ];
  atomicAdd(&xw[b * DQ + c], acc);
}

__global__ __launch_bounds__(128) void k_q2(const float* __restrict__ xw,
                                            const float* __restrict__ Wq,
                                            const float* __restrict__ bq,
                                            float* __restrict__ qv) {
  const int b = blockIdx.x, c = blockIdx.y * 128 + threadIdx.x;
  const float* xr = xw + b * DQ;
  float acc = 0.f, ss = 0.f;
  for (int k = 0; k < DQ; ++k) {
    float v = xr[k];
    acc += v * Wq[(size_t)k * DQ + c];
    ss += v * v;
  }
  const float inv = 1.0f / (sqrtf(ss) + 1e-6f);
  qv[b * DQ + c] = (acc * inv + bq[c]) * 0.125f;
}

__global__ void k_q3(const float* __restrict__ Wk, const float* __restrict__ bk,
                     const float* __restrict__ qv, float* __restrict__ qk,
                     float* __restrict__ cQ) {
  const int bh = blockIdx.x;
  const int b = bh / HQ, h = bh - b * HQ;
  const int tid = threadIdx.x;
  const float* q = qv + b * DQ + h * 64;
#pragma unroll
  for (int j = 0; j < 3; ++j) {
    int dd = tid + j * 256;
    float acc = 0.f;
    for (int j2 = 0; j2 < 64; ++j2) acc += Wk[(size_t)dd * DQ + h * 64 + j2] * q[j2];
    qk[(size_t)bh * DQ + dd] = acc;
  }
  if (tid == 0) {
    float acc = 0.f;
    for (int j2 = 0; j2 < 64; ++j2) acc += q[j2] * bk[h * 64 + j2];
    cQ[bh] = acc;
  }
}

// ---------------- K1: z = ybf @ WyT^T + by (bf16), rowsq += ssq ---------
// BM=256, BN=256, BK=64, 8 waves (2Mx4N, wave tile 128x64).
// Ring of 4 x 32KB quarter-slots, lead-3 staging, counted vmcnt(8).
// Swizzle f(r) = (r>>1)&3 -> ds_read_b128 hits all 8 bank-groups (2-way,
// free). [R10: this fix bought ~65us; yp ~80us]
__global__ __launch_bounds__(512, 1) void k_gemm_yp(const ushort_t* __restrict__ ybf,
                                                    const ushort_t* __restrict__ WyT,
                                                    const float* __restrict__ by,
                                                    ushort_t* __restrict__ z,
                                                    float* __restrict__ rowsqg) {
  __shared__ __align__(16) char smem[131072 + 1024];
  float* rowsq_l = (float*)(smem + 131072);
  const int tid = threadIdx.x, lane = tid & 63, wv = tid >> 6;
  const int wvM = wv >> 2, wvN = wv & 3;
  const int g = blockIdx.x;
  const int m = (g / 24) * 8 + (g & 7);
  const int n = (g >> 3) % 3;
  const int mBase = m * 256, nBase = n * 256;
  if (tid < 256) rowsq_l[tid] = 0.f;

  // staging sources: source chunk pre-swizzled with f(row) = ((lane>>3)&3)
  const int sr = lane >> 2;
  const int sc = (lane & 3) ^ ((lane >> 3) & 3);
  const ushort_t* aQ[2]; const ushort_t* bQ[2];
  int qDst[2];
#pragma unroll
  for (int j = 0; j < 2; ++j) {
    int r = wv * 32 + j * 16 + sr;
    aQ[j] = ybf + (size_t)(mBase + r) * DYQ + sc * 8;
    bQ[j] = WyT + (size_t)(nBase + r) * DYQ + sc * 8;
    qDst[j] = (wv * 32 + j * 16) * 64;
  }
  // fragment read offsets; phys chunk = q ^ ((r>>1)&3), r-base mult of 16
  const int q = lane >> 4;
  const int fsw = ((lane & 15) >> 1) & 3;
  int aFr[8], bFr[4];
#pragma unroll
  for (int mf = 0; mf < 8; ++mf) {
    int r = wvM * 128 + mf * 16 + (lane & 15);
    aFr[mf] = r * 64 + ((q ^ fsw) << 4);
  }
#pragma unroll
  for (int nf = 0; nf < 4; ++nf) {
    int r = wvN * 64 + nf * 16 + (lane & 15);
    bFr[nf] = 16384 + r * 64 + ((q ^ fsw) << 4);
  }

#define YP_STAGE(pp)                                                           \
  {                                                                            \
    char* db = smem + ((pp) & 3) * 32768;                                      \
    const int koff = ((pp) >> 1) * 64 + ((pp) & 1) * 32;                       \
    _Pragma("unroll") for (int j = 0; j < 2; ++j)                              \
        gload_lds16(aQ[j] + koff, db + qDst[j]);                               \
    _Pragma("unroll") for (int j = 0; j < 2; ++j)                              \
        gload_lds16(bQ[j] + koff, db + 16384 + qDst[j]);                       \
  }

  f32x4 acc[8][4] = {};
  YP_STAGE(0);
  YP_STAGE(1);
  YP_STAGE(2);
  asm volatile("s_waitcnt vmcnt(8)" ::: "memory");   // stage(0) landed
  __builtin_amdgcn_s_barrier();
  __builtin_amdgcn_sched_barrier(0);

  for (int t = 0; t < 16; ++t) {
#pragma unroll
    for (int ks = 0; ks < 2; ++ks) {
      const int p = 2 * t + ks;
      const char* cb = smem + (p & 3) * 32768;
      short8 af[8], bf[4];
#pragma unroll
      for (int mf = 0; mf < 8; ++mf) af[mf] = *(const short8*)(cb + aFr[mf]);
#pragma unroll
      for (int nf = 0; nf < 4; ++nf) bf[nf] = *(const short8*)(cb + bFr[nf]);
      if (p <= 28) YP_STAGE(p + 3);
      asm volatile("s_waitcnt lgkmcnt(0)" ::: "memory");
      __builtin_amdgcn_sched_barrier(0);
      __builtin_amdgcn_s_setprio(1);
#pragma unroll
      for (int nf = 0; nf < 4; ++nf)
#pragma unroll
        for (int mf = 0; mf < 8; ++mf)
          acc[mf][nf] = __builtin_amdgcn_mfma_f32_16x16x32_bf16(af[mf], bf[nf],
                                                                acc[mf][nf], 0, 0, 0);
      __builtin_amdgcn_s_setprio(0);
      __builtin_amdgcn_sched_barrier(0);
      if (p <= 28) {
        asm volatile("s_waitcnt vmcnt(8)" ::: "memory");   // stage(p+1) landed
      } else if (p == 29) {
        asm volatile("s_waitcnt vmcnt(4)" ::: "memory");
      } else {
        asm volatile("s_waitcnt vmcnt(0)" ::: "memory");
      }
      __builtin_amdgcn_s_barrier();
      __builtin_amdgcn_sched_barrier(0);
    }
  }
  __syncthreads();

  // ---- epilogue: +bias, z tile (256x256) -> LDS, row ssq partials ----
  float byv[4];
#pragma unroll
  for (int nf = 0; nf < 4; ++nf) byv[nf] = by[nBase + wvN * 64 + nf * 16 + (lane & 15)];
#pragma unroll
  for (int mf = 0; mf < 8; ++mf) {
#pragma unroll
    for (int rr = 0; rr < 4; ++rr) {
      int row_l = wvM * 128 + mf * 16 + (lane >> 4) * 4 + rr;
      float ss = 0.f;
#pragma unroll
      for (int nf = 0; nf < 4; ++nf) {
        float zv = acc[mf][nf][rr] + byv[nf];
        ss += zv * zv;
        int col_l = wvN * 64 + nf * 16 + (lane & 15);
        *(ushort_t*)(smem + row_l * 512 + col_l * 2) = f2bf(zv);
      }
#pragma unroll
      for (int o = 1; o < 16; o <<= 1) ss += __shfl_xor(ss, o, 64);
      if ((lane & 15) == 0) atomicAdd(&rowsq_l[row_l], ss);
    }
  }
  __syncthreads();
  if (tid < 256) atomicAdd(&rowsqg[mBase + tid], rowsq_l[tid]);
#pragma unroll
  for (int it = 0; it < 16; ++it) {
    int row = it * 16 + (tid >> 5);
    int ch = tid & 31;
    uint4 v = *(const uint4*)(smem + row * 512 + ch * 16);
    *(uint4*)(z + (size_t)(mBase + row) * DQ + nBase + ch * 8) = v;
  }
}

// ---------------- K2: windowed attention -> p[b,n,h,:] ------------------
__global__ __launch_bounds__(256) void k_attn(const ushort_t* __restrict__ z,
                                              const float* __restrict__ rowsqg,
                                              const float* __restrict__ qk,
                                              const float* __restrict__ cQ,
                                              ushort_t* __restrict__ p) {
  __shared__ __align__(16) char smem[16 * 1552 + 192 * 4 * 2 + 64];
  float* s_l = (float*)(smem + 16 * 1552);
  float* a_l = s_l + 192;
  float* inv_l = a_l + 192;
  const int bn = blockIdx.x, b = bn >> 9;
  const int tid = threadIdx.x;
  if (tid < 16) inv_l[tid] = 1.0f / (sqrtf(rowsqg[bn * 16 + tid]) + 1e-6f);
  for (int j = tid; j < 16 * 96; j += 256) {
    int w = j / 96, ch = j - w * 96;
    *(short8*)(smem + w * 1552 + ch * 16) =
        *(const short8*)(z + ((size_t)bn * 16 + w) * DQ + ch * 8);
  }
  __syncthreads();
  if (tid < 192) {  // (h,w): s = (z_w . qk~) * inv_w + cQ
    int h = tid >> 4, w = tid & 15;
    const float4* qkp = (const float4*)(qk + (size_t)(b * HQ + h) * DQ);
    float acc = 0.f;
    const char* yrow = smem + w * 1552;
    for (int dc = 0; dc < 192; ++dc) {
      float4 q4 = qkp[dc];
      uint2 hh = *(const uint2*)(yrow + dc * 8);
      acc += q4.x * bf2f((ushort_t)(hh.x & 0xffff));
      acc += q4.y * bf2f((ushort_t)(hh.x >> 16));
      acc += q4.z * bf2f((ushort_t)(hh.y & 0xffff));
      acc += q4.w * bf2f((ushort_t)(hh.y >> 16));
    }
    s_l[tid] = acc * inv_l[w] + cQ[b * HQ + h];
  }
  __syncthreads();
  if (tid < 12) {  // softmax over w; fold inv_w into weights
    float mx = -1e30f;
#pragma unroll
    for (int w = 0; w < 16; ++w) mx = fmaxf(mx, s_l[tid * 16 + w]);
    float sm = 0.f, ev[16];
#pragma unroll
    for (int w = 0; w < 16; ++w) {
      ev[w] = __expf(s_l[tid * 16 + w] - mx);
      sm += ev[w];
    }
    float rden = 1.0f / sm;
#pragma unroll
    for (int w = 0; w < 16; ++w) a_l[tid * 16 + w] = ev[w] * rden * inv_l[w];
  }
  __syncthreads();
  float zr[16][3];
#pragma unroll
  for (int w = 0; w < 16; ++w)
#pragma unroll
    for (int i = 0; i < 3; ++i)
      zr[w][i] = bf2f(*(const ushort_t*)(smem + w * 1552 + (tid + i * 256) * 2));
  for (int h = 0; h < HQ; ++h) {
    float acc0 = 0.f, acc1 = 0.f, acc2 = 0.f;
#pragma unroll
    for (int w = 0; w < 16; ++w) {
      float aw = a_l[h * 16 + w];
      acc0 += aw * zr[w][0];
      acc1 += aw * zr[w][1];
      acc2 += aw * zr[w][2];
    }
    size_t base = ((size_t)bn * HQ + h) * DQ + tid;
    p[base] = f2bf(acc0);
    p[base + 256] = f2bf(acc1);
    p[base + 512] = f2bf(acc2);
  }
}

// ---------------- K3: ctx[:, h*64:(h+1)*64] = p_h @ Wv_h + bv -----------
#define PV_TSZ 24576         // A 16KB + B 8KB
__global__ __launch_bounds__(256) void k_gemm_pv(const ushort_t* __restrict__ p,
                                                 const ushort_t* __restrict__ WvT,
                                                 const float* __restrict__ bv,
                                                 ushort_t* __restrict__ ctx) {
  __shared__ __align__(16) char smem[3 * PV_TSZ];
  const int tid = threadIdx.x, lane = tid & 63, wv = tid >> 6;
  const int wvM = wv >> 1, wvN = wv & 1;
  const int mBase = blockIdx.x * 128, h = blockIdx.y;
  const int l8 = lane >> 3;
  const int c8 = (lane & 7) ^ (l8 & 7);
  const ushort_t* aSrc[4]; const ushort_t* bSrc[2];
  int aDst[4], bDst[2];
#pragma unroll
  for (int j = 0; j < 4; ++j) {
    int r = wv * 32 + j * 8 + l8;
    aSrc[j] = p + ((size_t)(mBase + r) * HQ + h) * DQ + c8 * 8;
    aDst[j] = (wv * 32 + j * 8) * 128;
  }
#pragma unroll
  for (int j = 0; j < 2; ++j) {
    int r = wv * 16 + j * 8 + l8;
    bSrc[j] = WvT + (size_t)(h * 64 + r) * DQ + c8 * 8;
    bDst[j] = 16384 + (wv * 16 + j * 8) * 128;
  }
  const int q = lane >> 4;
  int aRowB[4], aSw[4], bRowB[2], bSw[2];
#pragma unroll
  for (int mf = 0; mf < 4; ++mf) {
    int r = wvM * 64 + mf * 16 + (lane & 15);
    aRowB[mf] = r * 128; aSw[mf] = r & 7;
  }
#pragma unroll
  for (int nf = 0; nf < 2; ++nf) {
    int r = wvN * 32 + nf * 16 + (lane & 15);
    bRowB[nf] = 16384 + r * 128; bSw[nf] = r & 7;
  }
#define PV_STAGE(dbuf, t)                                                      \
  {                                                                            \
    char* db = smem + (dbuf) * PV_TSZ;                                         \
    _Pragma("unroll") for (int j = 0; j < 4; ++j)                              \
        gload_lds16(aSrc[j] + (t) * 64, db + aDst[j]);                         \
    _Pragma("unroll") for (int j = 0; j < 2; ++j)                              \
        gload_lds16(bSrc[j] + (t) * 64, db + bDst[j]);                         \
  }
  f32x4 acc[4][2] = {};
  PV_STAGE(0, 0);
  PV_STAGE(1, 1);
  int bR = 0, bS = 2;
  for (int t = 0; t < 12; ++t) {
    if (t < 11) {
      asm volatile("s_waitcnt vmcnt(6)" ::: "memory");
    } else {
      asm volatile("s_waitcnt vmcnt(0)" ::: "memory");
    }
    __builtin_amdgcn_s_barrier();
    __builtin_amdgcn_sched_barrier(0);
    if (t + 2 < 12) PV_STAGE(bS, t + 2);
    const char* cur = smem + bR * PV_TSZ;
#pragma unroll
    for (int ks = 0; ks < 2; ++ks) {
      short8 af[4], bf[2];
#pragma unroll
      for (int mf = 0; mf < 4; ++mf)
        af[mf] = *(const short8*)(cur + aRowB[mf] + (((ks * 4 + q) ^ aSw[mf]) << 4));
#pragma unroll
      for (int nf = 0; nf < 2; ++nf)
        bf[nf] = *(const short8*)(cur + bRowB[nf] + (((ks * 4 + q) ^ bSw[nf]) << 4));
#pragma unroll
      for (int nf = 0; nf < 2; ++nf)
#pragma unroll
        for (int mf = 0; mf < 4; ++mf)
          acc[mf][nf] = __builtin_amdgcn_mfma_f32_16x16x32_bf16(af[mf], bf[nf],
                                                                acc[mf][nf], 0, 0, 0);
    }
    bR = (bR == 2) ? 0 : bR + 1;
    bS = (bS == 2) ? 0 : bS + 1;
  }
#pragma unroll
  for (int nf = 0; nf < 2; ++nf) {
    int col = h * 64 + wvN * 32 + nf * 16 + (lane & 15);
    float bvv = bv[col];
#pragma unroll
    for (int mf = 0; mf < 4; ++mf)
#pragma unroll
      for (int rr = 0; rr < 4; ++rr) {
        int row = mBase + wvM * 64 + mf * 16 + (lane >> 4) * 4 + rr;
        ctx[(size_t)row * DQ + col] = f2bf(acc[mf][nf][rr] + bvv);
      }
  }
}

// ---------------- K4: o = ctx @ Wo + bo (fp32) + row s1/s2 atomics ------
__global__ __launch_bounds__(256) void k_gemm_o(const ushort_t* __restrict__ ctx,
                                                const ushort_t* __restrict__ WoT,
                                                const float* __restrict__ bo,
                                                float* __restrict__ o,
                                                float* __restrict__ oS12) {
  __shared__ __align__(16) char smem[3 * PV_TSZ];
  const int tid = threadIdx.x, lane = tid & 63, wv = tid >> 6;
  const int wvM = wv >> 1, wvN = wv & 1;
  const int mBase = blockIdx.x * 128, nBase = blockIdx.y * 64;
  const int l8 = lane >> 3;
  const int c8 = (lane & 7) ^ (l8 & 7);
  const ushort_t* aSrc[4]; const ushort_t* bSrc[2];
  int aDst[4], bDst[2];
#pragma unroll
  for (int j = 0; j < 4; ++j) {
    int r = wv * 32 + j * 8 + l8;
    aSrc[j] = ctx + (size_t)(mBase + r) * DQ + c8 * 8;
    aDst[j] = (wv * 32 + j * 8) * 128;
  }
#pragma unroll
  for (int j = 0; j < 2; ++j) {
    int r = wv * 16 + j * 8 + l8;
    bSrc[j] = WoT + (size_t)(nBase + r) * DQ + c8 * 8;
    bDst[j] = 16384 + (wv * 16 + j * 8) * 128;
  }
  const int q = lane >> 4;
  int aRowB[4], aSw[4], bRowB[2], bSw[2];
#pragma unroll
  for (int mf = 0; mf < 4; ++mf) {
    int r = wvM * 64 + mf * 16 + (lane & 15);
    aRowB[mf] = r * 128; aSw[mf] = r & 7;
  }
#pragma unroll
  for (int nf = 0; nf < 2; ++nf) {
    int r = wvN * 32 + nf * 16 + (lane & 15);
    bRowB[nf] = 16384 + r * 128; bSw[nf] = r & 7;
  }
  f32x4 acc[4][2] = {};
#define O_STAGE(dbuf, t)                                                       \
  {                                                                            \
    char* db = smem + (dbuf) * PV_TSZ;                                         \
    _Pragma("unroll") for (int j = 0; j < 4; ++j)                              \
        gload_lds16(aSrc[j] + (t) * 64, db + aDst[j]);                         \
    _Pragma("unroll") for (int j = 0; j < 2; ++j)                              \
        gload_lds16(bSrc[j] + (t) * 64, db + bDst[j]);                         \
  }
  O_STAGE(0, 0);
  O_STAGE(1, 1);
  int bR = 0, bS = 2;
  for (int t = 0; t < 12; ++t) {
    if (t < 11) {
      asm volatile("s_waitcnt vmcnt(6)" ::: "memory");
    } else {
      asm volatile("s_waitcnt vmcnt(0)" ::: "memory");
    }
    __builtin_amdgcn_s_barrier();
    __builtin_amdgcn_sched_barrier(0);
    if (t + 2 < 12) O_STAGE(bS, t + 2);
    const char* cur = smem + bR * PV_TSZ;
#pragma unroll
    for (int ks = 0; ks < 2; ++ks) {
      short8 af[4], bf[2];
#pragma unroll
      for (int mf = 0; mf < 4; ++mf)
        af[mf] = *(const short8*)(cur + aRowB[mf] + (((ks * 4 + q) ^ aSw[mf]) << 4));
#pragma unroll
      for (int nf = 0; nf < 2; ++nf)
        bf[nf] = *(const short8*)(cur + bRowB[nf] + (((ks * 4 + q) ^ bSw[nf]) << 4));
#pragma unroll
      for (int nf = 0; nf < 2; ++nf)
#pragma unroll
        for (int mf = 0; mf < 4; ++mf)
          acc[mf][nf] = __builtin_amdgcn_mfma_f32_16x16x32_bf16(af[mf], bf[nf],
                                                                acc[mf][nf], 0, 0, 0);
    }
    bR = (bR == 2) ? 0 : bR + 1;
    bS = (bS == 2) ? 0 : bS + 1;
  }
  float bo0 = bo[nBase + wvN * 32 + (lane & 15)];
  float bo1 = bo[nBase + wvN * 32 + 16 + (lane & 15)];
#pragma unroll
  for (int mf = 0; mf < 4; ++mf)
#pragma unroll
    for (int rr = 0; rr < 4; ++rr) {
      int row = mBase + wvM * 64 + mf * 16 + (lane >> 4) * 4 + rr;
      float z0 = acc[mf][0][rr] + bo0;
      float z1 = acc[mf][1][rr] + bo1;
      o[(size_t)row * DQ + nBase + wvN * 32 + (lane & 15)] = z0;
      o[(size_t)row * DQ + nBase + wvN * 32 + 16 + (lane & 15)] = z1;
      float s1 = z0 + z1, s2 = z0 * z0 + z1 * z1;
#pragma unroll
      for (int ofs = 1; ofs < 16; ofs <<= 1) {
        s1 += __shfl_xor(s1, ofs, 64);
        s2 += __shfl_xor(s2, ofs, 64);
      }
      if ((lane & 15) == 0) {
        atomicAdd(&oS12[row], s1);
        atomicAdd(&oS12[BN_ROWS + row], s2);
      }
    }
}

// K5: LayerNorm finalize + prompt broadcast -> out
__global__ __launch_bounds__(256) void k_out(const float* __restrict__ o,
                                             const float* __restrict__ oS12,
                                             const float* __restrict__ ln_g,
                                             const float* __restrict__ ln_b,
                                             const float* __restrict__ prompt,
                                             float* __restrict__ out) {
  const int row = blockIdx.x;
  const int tid = threadIdx.x;
  float mu = oS12[row] * (1.0f / DQ);
  float va = oS12[BN_ROWS + row] * (1.0f / DQ) - mu * mu;
  float rstd = rsqrtf(va + 1e-6f);
  int b = row >> 9, n = row & 511;
  size_t obase = ((size_t)b * (NXQ * (PQ + 1)) + (size_t)n * (PQ + 1)) * DQ;
#pragma unroll
  for (int j = 0; j < 3; ++j) {
    int col = tid + j * 256;
    out[obase + col] = (o[(size_t)row * DQ + col] - mu) * rstd * ln_g[col] + ln_b[col];
  }
#pragma unroll
  for (int pi = 0; pi < PQ; ++pi)
#pragma unroll
    for (int j = 0; j < 3; ++j) {
      int col = tid + j * 256;
      out[obase + (size_t)(1 + pi) * DQ + col] = prompt[pi * DQ + col];
    }
}

extern "C" void kernel_launch(void* const* d_in, const int* in_sizes, int n_in,
                              void* d_out, int out_size, void* d_ws, size_t ws_size,
                              hipStream_t stream) {
  (void)in_sizes; (void)n_in; (void)out_size; (void)ws_size;
  const float* x    = (const float*)d_in[0];
  const float* y    = (const float*)d_in[1];
  const float* Wx   = (const float*)d_in[2];
  const float* bx   = (const float*)d_in[3];
  const float* Wy   = (const float*)d_in[4];
  const float* by   = (const float*)d_in[5];
  const float* prom = (const float*)d_in[6];
  const float* Wq   = (const float*)d_in[7];
  const float* bq   = (const float*)d_in[8];
  const float* Wk   = (const float*)d_in[9];
  const float* bk   = (const float*)d_in[10];
  const float* Wv   = (const float*)d_in[11];
  const float* bv   = (const float*)d_in[12];
  const float* Wo   = (const float*)d_in[13];
  const float* bo   = (const float*)d_in[14];
  const float* lng  = (const float*)d_in[15];
  const float* lnb  = (const float*)d_in[16];
  float* out = (float*)d_out;
  char* ws = (char*)d_ws;

  // ---- workspace layout (aliased) ----
  size_t oWyT = 0;
  size_t oWvT = oWyT + (size_t)DQ * DYQ * 2;
  size_t oWoT = oWvT + (size_t)DQ * DQ * 2;
  size_t oXw  = oWoT + (size_t)DQ * DQ * 2;
  size_t oQ   = oXw + (size_t)BQ * DQ * 4 + 256;
  size_t oQK  = oQ + (size_t)BQ * DQ * 4;
  size_t oC   = oQK + (size_t)BQ * HQ * DQ * 4;
  size_t oRq  = oC + 1024;
  size_t oS   = oRq + (size_t)MY * 4;
  size_t oYbf = oS + (size_t)2 * BN_ROWS * 4;
  size_t oZ   = oYbf + (size_t)MY * DYQ * 2;
  size_t oP   = oYbf;                                 // alias (ybf dead)
  size_t oCtx = oYbf + (size_t)BN_ROWS * HQ * DQ * 2;
  size_t oO   = oZ;                                   // alias (z dead)

  ushort_t* WyT = (ushort_t*)(ws + oWyT);
  ushort_t* WvT = (ushort_t*)(ws + oWvT);
  ushort_t* WoT = (ushort_t*)(ws + oWoT);
  float* xw  = (float*)(ws + oXw);
  float* qv  = (float*)(ws + oQ);
  float* qk  = (float*)(ws + oQK);
  float* cQ  = (float*)(ws + oC);
  float* rowsq = (float*)(ws + oRq);
  float* oS12  = (float*)(ws + oS);
  ushort_t* ybf  = (ushort_t*)(ws + oYbf);
  ushort_t* zbuf = (ushort_t*)(ws + oZ);
  ushort_t* p    = (ushort_t*)(ws + oP);
  ushort_t* ctx  = (ushort_t*)(ws + oCtx);
  float* obuf    = (float*)(ws + oO);

  k_conv<<<dim3(4096), dim3(256), 0, stream>>>(y, Wy, Wv, Wo, ybf, WyT, WvT, WoT,
                                               rowsq, oS12, xw);
  k_q1<<<dim3(BQ, 6, 8), dim3(128), 0, stream>>>(x, Wx, bx, xw);
  k_q2<<<dim3(BQ, 6), dim3(128), 0, stream>>>(xw, Wq, bq, qv);
  k_q3<<<dim3(BQ * HQ), dim3(256), 0, stream>>>(Wk, bk, qv, qk, cQ);
  k_gemm_yp<<<dim3(768), dim3(512), 0, stream>>>(ybf, WyT, by, zbuf, rowsq);
  k_attn<<<dim3(BN_ROWS), dim3(256), 0, stream>>>(zbuf, rowsq, qk, cQ, p);
  k_gemm_pv<<<dim3(BN_ROWS / 128, HQ), dim3(256), 0, stream>>>(p, WvT, bv, ctx);
  k_gemm_o<<<dim3(BN_ROWS / 128, DQ / 64), dim3(256), 0, stream>>>(ctx, WoT, bo, obuf, oS12);
  k_out<<<dim3(BN_ROWS), dim3(256), 0, stream>>>(obuf, oS12, lng, lnb, prom, out);
}

// Round 12
// 440.866 us; speedup vs baseline: 1.2086x; 1.0105x over previous
//
#include <hip/hip_runtime.h>
#include <stdint.h>

// Problem constants
#define BQ 8
#define NXQ 512
#define WQ 16
#define DXQ 1536
#define DYQ 1024
#define DQ 768
#define HQ 12
#define PQ 8
// derived
#define MY 65536            // B*NX*W rows of y
#define BN_ROWS 4096        // B*NX

typedef __attribute__((ext_vector_type(8))) short short8;
typedef __attribute__((ext_vector_type(4))) float f32x4;
typedef unsigned short ushort_t;
typedef unsigned int uint_t;

__device__ __forceinline__ ushort_t f2bf(float f) {
  uint_t u = __float_as_uint(f);
  u += 0x7FFFu + ((u >> 16) & 1u);   // RNE
  return (ushort_t)(u >> 16);
}
__device__ __forceinline__ float bf2f(ushort_t h) {
  return __uint_as_float(((uint_t)h) << 16);
}
__device__ __forceinline__ void gload_lds16(const void* g, void* l) {
  __builtin_amdgcn_global_load_lds(
      (__attribute__((address_space(1))) unsigned int*)(g),
      (__attribute__((address_space(3))) unsigned int*)(l), 16, 0, 0);
}

// ---------------- K0: y->bf16, weight transposes, zero accumulators -----
__global__ void k_conv(const float* __restrict__ y, const float* __restrict__ Wy,
                       const float* __restrict__ Wv, const float* __restrict__ Wo,
                       ushort_t* __restrict__ ybf, ushort_t* __restrict__ WyT,
                       ushort_t* __restrict__ WvT, ushort_t* __restrict__ WoT,
                       float* __restrict__ rowsq, float* __restrict__ oS12,
                       float* __restrict__ xw) {
  const int gstride = gridDim.x * blockDim.x;
  const int g0 = blockIdx.x * blockDim.x + threadIdx.x;
  // y fp32 -> bf16
  const int NY8 = MY * DYQ / 8;
  for (int i = g0; i < NY8; i += gstride) {
    const float4* s = (const float4*)(y + (size_t)i * 8);
    float4 f0 = s[0], f1 = s[1];
    short8 hv;
    hv[0] = (short)f2bf(f0.x); hv[1] = (short)f2bf(f0.y);
    hv[2] = (short)f2bf(f0.z); hv[3] = (short)f2bf(f0.w);
    hv[4] = (short)f2bf(f1.x); hv[5] = (short)f2bf(f1.y);
    hv[6] = (short)f2bf(f1.z); hv[7] = (short)f2bf(f1.w);
    *(short8*)(ybf + (size_t)i * 8) = hv;
  }
  // zeros
  for (int i = g0; i < MY; i += gstride) rowsq[i] = 0.f;
  for (int i = g0; i < 2 * BN_ROWS; i += gstride) oS12[i] = 0.f;
  for (int i = g0; i < BQ * DQ; i += gstride) xw[i] = 0.f;
  // weight transposes (bf16)
  const int N1 = DQ * DYQ;
  const int N2 = DQ * DQ;
  const int total = N1 + 2 * N2;
  for (int i = g0; i < total; i += gstride) {
    if (i < N1) {
      int n = i / DYQ, k = i - n * DYQ;
      WyT[i] = f2bf(Wy[k * DQ + n]);
    } else if (i < N1 + N2) {
      int j = i - N1;
      int n = j / DQ, k = j - n * DQ;
      WvT[j] = f2bf(Wv[k * DQ + n]);
    } else {
      int j = i - N1 - N2;
      int n = j / DQ, k = j - n * DQ;
      WoT[j] = f2bf(Wo[k * DQ + n]);
    }
  }
}

// ---------------- q-chain ------------------------------------------------
__global__ __launch_bounds__(128) void k_q1(const float* __restrict__ x,
                                            const float* __restrict__ Wx,
                                            const float* __restrict__ bx,
                                            float* __restrict__ xw) {
  const int b = blockIdx.x, c = blockIdx.y * 128 + threadIdx.x;
  const int kc = blockIdx.z;
  const float* xr = x + (size_t)b * NXQ * DXQ + kc * 192;
  const float* wp = Wx + (size_t)kc * 192 * DQ + c;
  float acc = (kc == 0) ? bx[c] : 0.f;
  for (int k = 0; k < 192; ++k) acc += xr[k] * wp[(size_t)k * DQ];
  atomicAdd(&xw[b * DQ + c], acc);
}

__global__ __launch_bounds__(128) void k_q2(const float* __restrict__ xw,
                                            const float* __restrict__ Wq,
                                            const float* __restrict__ bq,
                                            float* __restrict__ qv) {
  const int b = blockIdx.x, c = blockIdx.y * 128 + threadIdx.x;
  const float* xr = xw + b * DQ;
  float acc = 0.f, ss = 0.f;
  for (int k = 0; k < DQ; ++k) {
    float v = xr[k];
    acc += v * Wq[(size_t)k * DQ + c];
    ss += v * v;
  }
  const float inv = 1.0f / (sqrtf(ss) + 1e-6f);
  qv[b * DQ + c] = (acc * inv + bq[c]) * 0.125f;
}

__global__ void k_q3(const float* __restrict__ Wk, const float* __restrict__ bk,
                     const float* __restrict__ qv, float* __restrict__ qk,
                     float* __restrict__ cQ) {
  const int bh = blockIdx.x;
  const int b = bh / HQ, h = bh - b * HQ;
  const int tid = threadIdx.x;
  const float* q = qv + b * DQ + h * 64;
#pragma unroll
  for (int j = 0; j < 3; ++j) {
    int dd = tid + j * 256;
    float acc = 0.f;
    for (int j2 = 0; j2 < 64; ++j2) acc += Wk[(size_t)dd * DQ + h * 64 + j2] * q[j2];
    qk[(size_t)bh * DQ + dd] = acc;
  }
  if (tid == 0) {
    float acc = 0.f;
    for (int j2 = 0; j2 < 64; ++j2) acc += q[j2] * bk[h * 64 + j2];
    cQ[bh] = acc;
  }
}

// ---------------- K1: z = ybf @ WyT^T + by (bf16), rowsq += ssq ---------
// BM=128, BN=256, BK=32, 8 waves (2Mx4N, wave tile 64x64).
// LDS: ring of 3 x 24KB slots (A 8KB + B 16KB), lead-2 staging, counted
// vmcnt(3) -> 72KB LDS => 2 blocks/CU (the occupancy experiment).
// Swizzle f(r) = (r>>1)&3 (2-way bank-free ds_read_b128).
__global__ __launch_bounds__(512, 4) void k_gemm_yp(const ushort_t* __restrict__ ybf,
                                                    const ushort_t* __restrict__ WyT,
                                                    const float* __restrict__ by,
                                                    ushort_t* __restrict__ z,
                                                    float* __restrict__ rowsqg) {
  __shared__ __align__(16) char smem[3 * 24576 + 512];
  float* rowsq_l = (float*)(smem + 3 * 24576);
  const int tid = threadIdx.x, lane = tid & 63, wv = tid >> 6;
  const int wvM = wv >> 2, wvN = wv & 3;
  const int g = blockIdx.x;
  const int m = (g / 24) * 8 + (g & 7);
  const int n = (g >> 3) % 3;
  const int mBase = m * 128, nBase = n * 256;
  if (tid < 128) rowsq_l[tid] = 0.f;

  // staging sources (pre-swizzled chunk): A 1 gload/thread, B 2.
  const int srow = tid >> 2;                       // 0..127
  const int schk = (tid & 3) ^ ((tid >> 3) & 3);   // logical chunk for phys tid&3
  const ushort_t* aS = ybf + (size_t)(mBase + srow) * DYQ + schk * 8;
  const ushort_t* bS0 = WyT + (size_t)(nBase + srow) * DYQ + schk * 8;
  const ushort_t* bS1 = WyT + (size_t)(nBase + 128 + srow) * DYQ + schk * 8;
  const int sDst = tid * 16;                       // linear in-slot dest (A)
  // fragment read offsets; phys chunk = q ^ ((r>>1)&3); frag bases mult 16
  const int q = lane >> 4;
  const int fsw = ((lane & 15) >> 1) & 3;
  int aFr[4], bFr[4];
#pragma unroll
  for (int mf = 0; mf < 4; ++mf) {
    int r = wvM * 64 + mf * 16 + (lane & 15);
    aFr[mf] = r * 64 + ((q ^ fsw) << 4);
  }
#pragma unroll
  for (int nf = 0; nf < 4; ++nf) {
    int r = wvN * 64 + nf * 16 + (lane & 15);
    bFr[nf] = 8192 + r * 64 + ((q ^ fsw) << 4);
  }

#define YP_STAGE(pp)                                                           \
  {                                                                            \
    char* db = smem + ((pp) % 3) * 24576;                                      \
    const int koff = (pp) * 32;                                                \
    gload_lds16(aS + koff, db + sDst);                                         \
    gload_lds16(bS0 + koff, db + 8192 + sDst);                                 \
    gload_lds16(bS1 + koff, db + 16384 + sDst);                                \
  }

  f32x4 acc[4][4] = {};
  YP_STAGE(0);
  YP_STAGE(1);
  asm volatile("s_waitcnt vmcnt(3)" ::: "memory");   // stage(0) landed
  __builtin_amdgcn_s_barrier();
  __builtin_amdgcn_sched_barrier(0);

  for (int p = 0; p < 32; ++p) {
    const char* cb = smem + (p % 3) * 24576;
    short8 af[4], bf[4];
#pragma unroll
    for (int mf = 0; mf < 4; ++mf) af[mf] = *(const short8*)(cb + aFr[mf]);
#pragma unroll
    for (int nf = 0; nf < 4; ++nf) bf[nf] = *(const short8*)(cb + bFr[nf]);
    if (p <= 29) YP_STAGE(p + 2);
    asm volatile("s_waitcnt lgkmcnt(0)" ::: "memory");
    __builtin_amdgcn_sched_barrier(0);
    __builtin_amdgcn_s_setprio(1);
#pragma unroll
    for (int nf = 0; nf < 4; ++nf)
#pragma unroll
      for (int mf = 0; mf < 4; ++mf)
        acc[mf][nf] = __builtin_amdgcn_mfma_f32_16x16x32_bf16(af[mf], bf[nf],
                                                              acc[mf][nf], 0, 0, 0);
    __builtin_amdgcn_s_setprio(0);
    __builtin_amdgcn_sched_barrier(0);
    if (p <= 29) {
      asm volatile("s_waitcnt vmcnt(3)" ::: "memory");   // stage(p+1) landed
    } else {
      asm volatile("s_waitcnt vmcnt(0)" ::: "memory");
    }
    __builtin_amdgcn_s_barrier();
    __builtin_amdgcn_sched_barrier(0);
  }
  __syncthreads();

  // ---- epilogue: +bias, z tile (128x256) -> LDS, row ssq partials ----
  float byv[4];
#pragma unroll
  for (int nf = 0; nf < 4; ++nf) byv[nf] = by[nBase + wvN * 64 + nf * 16 + (lane & 15)];
#pragma unroll
  for (int mf = 0; mf < 4; ++mf) {
#pragma unroll
    for (int rr = 0; rr < 4; ++rr) {
      int row_l = wvM * 64 + mf * 16 + (lane >> 4) * 4 + rr;
      float ss = 0.f;
#pragma unroll
      for (int nf = 0; nf < 4; ++nf) {
        float zv = acc[mf][nf][rr] + byv[nf];
        ss += zv * zv;
        int col_l = wvN * 64 + nf * 16 + (lane & 15);
        *(ushort_t*)(smem + row_l * 512 + col_l * 2) = f2bf(zv);
      }
#pragma unroll
      for (int o = 1; o < 16; o <<= 1) ss += __shfl_xor(ss, o, 64);
      if ((lane & 15) == 0) atomicAdd(&rowsq_l[row_l], ss);
    }
  }
  __syncthreads();
  if (tid < 128) atomicAdd(&rowsqg[mBase + tid], rowsq_l[tid]);
#pragma unroll
  for (int it = 0; it < 8; ++it) {
    int row = it * 16 + (tid >> 5);
    int ch = tid & 31;
    uint4 v = *(const uint4*)(smem + row * 512 + ch * 16);
    *(uint4*)(z + (size_t)(mBase + row) * DQ + nBase + ch * 8) = v;
  }
}

// ---------------- K2: windowed attention -> p[b,n,h,:] ------------------
__global__ __launch_bounds__(256) void k_attn(const ushort_t* __restrict__ z,
                                              const float* __restrict__ rowsqg,
                                              const float* __restrict__ qk,
                                              const float* __restrict__ cQ,
                                              ushort_t* __restrict__ p) {
  __shared__ __align__(16) char smem[16 * 1552 + 192 * 4 * 2 + 64];
  float* s_l = (float*)(smem + 16 * 1552);
  float* a_l = s_l + 192;
  float* inv_l = a_l + 192;
  const int bn = blockIdx.x, b = bn >> 9;
  const int tid = threadIdx.x;
  if (tid < 16) inv_l[tid] = 1.0f / (sqrtf(rowsqg[bn * 16 + tid]) + 1e-6f);
  for (int j = tid; j < 16 * 96; j += 256) {
    int w = j / 96, ch = j - w * 96;
    *(short8*)(smem + w * 1552 + ch * 16) =
        *(const short8*)(z + ((size_t)bn * 16 + w) * DQ + ch * 8);
  }
  __syncthreads();
  if (tid < 192) {  // (h,w): s = (z_w . qk~) * inv_w + cQ
    int h = tid >> 4, w = tid & 15;
    const float4* qkp = (const float4*)(qk + (size_t)(b * HQ + h) * DQ);
    float acc = 0.f;
    const char* yrow = smem + w * 1552;
    for (int dc = 0; dc < 192; ++dc) {
      float4 q4 = qkp[dc];
      uint2 hh = *(const uint2*)(yrow + dc * 8);
      acc += q4.x * bf2f((ushort_t)(hh.x & 0xffff));
      acc += q4.y * bf2f((ushort_t)(hh.x >> 16));
      acc += q4.z * bf2f((ushort_t)(hh.y & 0xffff));
      acc += q4.w * bf2f((ushort_t)(hh.y >> 16));
    }
    s_l[tid] = acc * inv_l[w] + cQ[b * HQ + h];
  }
  __syncthreads();
  if (tid < 12) {  // softmax over w; fold inv_w into weights
    float mx = -1e30f;
#pragma unroll
    for (int w = 0; w < 16; ++w) mx = fmaxf(mx, s_l[tid * 16 + w]);
    float sm = 0.f, ev[16];
#pragma unroll
    for (int w = 0; w < 16; ++w) {
      ev[w] = __expf(s_l[tid * 16 + w] - mx);
      sm += ev[w];
    }
    float rden = 1.0f / sm;
#pragma unroll
    for (int w = 0; w < 16; ++w) a_l[tid * 16 + w] = ev[w] * rden * inv_l[w];
  }
  __syncthreads();
  float zr[16][3];
#pragma unroll
  for (int w = 0; w < 16; ++w)
#pragma unroll
    for (int i = 0; i < 3; ++i)
      zr[w][i] = bf2f(*(const ushort_t*)(smem + w * 1552 + (tid + i * 256) * 2));
  for (int h = 0; h < HQ; ++h) {
    float acc0 = 0.f, acc1 = 0.f, acc2 = 0.f;
#pragma unroll
    for (int w = 0; w < 16; ++w) {
      float aw = a_l[h * 16 + w];
      acc0 += aw * zr[w][0];
      acc1 += aw * zr[w][1];
      acc2 += aw * zr[w][2];
    }
    size_t base = ((size_t)bn * HQ + h) * DQ + tid;
    p[base] = f2bf(acc0);
    p[base + 256] = f2bf(acc1);
    p[base + 512] = f2bf(acc2);
  }
}

// ---------------- K3: ctx[:, h*64:(h+1)*64] = p_h @ Wv_h + bv -----------
#define PV_TSZ 24576         // A 16KB + B 8KB
__global__ __launch_bounds__(256) void k_gemm_pv(const ushort_t* __restrict__ p,
                                                 const ushort_t* __restrict__ WvT,
                                                 const float* __restrict__ bv,
                                                 ushort_t* __restrict__ ctx) {
  __shared__ __align__(16) char smem[3 * PV_TSZ];
  const int tid = threadIdx.x, lane = tid & 63, wv = tid >> 6;
  const int wvM = wv >> 1, wvN = wv & 1;
  const int mBase = blockIdx.x * 128, h = blockIdx.y;
  const int l8 = lane >> 3;
  const int c8 = (lane & 7) ^ (l8 & 7);
  const ushort_t* aSrc[4]; const ushort_t* bSrc[2];
  int aDst[4], bDst[2];
#pragma unroll
  for (int j = 0; j < 4; ++j) {
    int r = wv * 32 + j * 8 + l8;
    aSrc[j] = p + ((size_t)(mBase + r) * HQ + h) * DQ + c8 * 8;
    aDst[j] = (wv * 32 + j * 8) * 128;
  }
#pragma unroll
  for (int j = 0; j < 2; ++j) {
    int r = wv * 16 + j * 8 + l8;
    bSrc[j] = WvT + (size_t)(h * 64 + r) * DQ + c8 * 8;
    bDst[j] = 16384 + (wv * 16 + j * 8) * 128;
  }
  const int q = lane >> 4;
  int aRowB[4], aSw[4], bRowB[2], bSw[2];
#pragma unroll
  for (int mf = 0; mf < 4; ++mf) {
    int r = wvM * 64 + mf * 16 + (lane & 15);
    aRowB[mf] = r * 128; aSw[mf] = r & 7;
  }
#pragma unroll
  for (int nf = 0; nf < 2; ++nf) {
    int r = wvN * 32 + nf * 16 + (lane & 15);
    bRowB[nf] = 16384 + r * 128; bSw[nf] = r & 7;
  }
#define PV_STAGE(dbuf, t)                                                      \
  {                                                                            \
    char* db = smem + (dbuf) * PV_TSZ;                                         \
    _Pragma("unroll") for (int j = 0; j < 4; ++j)                              \
        gload_lds16(aSrc[j] + (t) * 64, db + aDst[j]);                         \
    _Pragma("unroll") for (int j = 0; j < 2; ++j)                              \
        gload_lds16(bSrc[j] + (t) * 64, db + bDst[j]);                         \
  }
  f32x4 acc[4][2] = {};
  PV_STAGE(0, 0);
  PV_STAGE(1, 1);
  int bR = 0, bS = 2;
  for (int t = 0; t < 12; ++t) {
    if (t < 11) {
      asm volatile("s_waitcnt vmcnt(6)" ::: "memory");
    } else {
      asm volatile("s_waitcnt vmcnt(0)" ::: "memory");
    }
    __builtin_amdgcn_s_barrier();
    __builtin_amdgcn_sched_barrier(0);
    if (t + 2 < 12) PV_STAGE(bS, t + 2);
    const char* cur = smem + bR * PV_TSZ;
#pragma unroll
    for (int ks = 0; ks < 2; ++ks) {
      short8 af[4], bf[2];
#pragma unroll
      for (int mf = 0; mf < 4; ++mf)
        af[mf] = *(const short8*)(cur + aRowB[mf] + (((ks * 4 + q) ^ aSw[mf]) << 4));
#pragma unroll
      for (int nf = 0; nf < 2; ++nf)
        bf[nf] = *(const short8*)(cur + bRowB[nf] + (((ks * 4 + q) ^ bSw[nf]) << 4));
#pragma unroll
      for (int nf = 0; nf < 2; ++nf)
#pragma unroll
        for (int mf = 0; mf < 4; ++mf)
          acc[mf][nf] = __builtin_amdgcn_mfma_f32_16x16x32_bf16(af[mf], bf[nf],
                                                                acc[mf][nf], 0, 0, 0);
    }
    bR = (bR == 2) ? 0 : bR + 1;
    bS = (bS == 2) ? 0 : bS + 1;
  }
#pragma unroll
  for (int nf = 0; nf < 2; ++nf) {
    int col = h * 64 + wvN * 32 + nf * 16 + (lane & 15);
    float bvv = bv[col];
#pragma unroll
    for (int mf = 0; mf < 4; ++mf)
#pragma unroll
      for (int rr = 0; rr < 4; ++rr) {
        int row = mBase + wvM * 64 + mf * 16 + (lane >> 4) * 4 + rr;
        ctx[(size_t)row * DQ + col] = f2bf(acc[mf][nf][rr] + bvv);
      }
  }
}

// ---------------- K4: o = ctx @ Wo + bo (fp32) + row s1/s2 atomics ------
__global__ __launch_bounds__(256) void k_gemm_o(const ushort_t* __restrict__ ctx,
                                                const ushort_t* __restrict__ WoT,
                                                const float* __restrict__ bo,
                                                float* __restrict__ o,
                                                float* __restrict__ oS12) {
  __shared__ __align__(16) char smem[3 * PV_TSZ];
  const int tid = threadIdx.x, lane = tid & 63, wv = tid >> 6;
  const int wvM = wv >> 1, wvN = wv & 1;
  const int mBase = blockIdx.x * 128, nBase = blockIdx.y * 64;
  const int l8 = lane >> 3;
  const int c8 = (lane & 7) ^ (l8 & 7);
  const ushort_t* aSrc[4]; const ushort_t* bSrc[2];
  int aDst[4], bDst[2];
#pragma unroll
  for (int j = 0; j < 4; ++j) {
    int r = wv * 32 + j * 8 + l8;
    aSrc[j] = ctx + (size_t)(mBase + r) * DQ + c8 * 8;
    aDst[j] = (wv * 32 + j * 8) * 128;
  }
#pragma unroll
  for (int j = 0; j < 2; ++j) {
    int r = wv * 16 + j * 8 + l8;
    bSrc[j] = WoT + (size_t)(nBase + r) * DQ + c8 * 8;
    bDst[j] = 16384 + (wv * 16 + j * 8) * 128;
  }
  const int q = lane >> 4;
  int aRowB[4], aSw[4], bRowB[2], bSw[2];
#pragma unroll
  for (int mf = 0; mf < 4; ++mf) {
    int r = wvM * 64 + mf * 16 + (lane & 15);
    aRowB[mf] = r * 128; aSw[mf] = r & 7;
  }
#pragma unroll
  for (int nf = 0; nf < 2; ++nf) {
    int r = wvN * 32 + nf * 16 + (lane & 15);
    bRowB[nf] = 16384 + r * 128; bSw[nf] = r & 7;
  }
  f32x4 acc[4][2] = {};
#define O_STAGE(dbuf, t)                                                       \
  {                                                                            \
    char* db = smem + (dbuf) * PV_TSZ;                                         \
    _Pragma("unroll") for (int j = 0; j < 4; ++j)                              \
        gload_lds16(aSrc[j] + (t) * 64, db + aDst[j]);                         \
    _Pragma("unroll") for (int j = 0; j < 2; ++j)                              \
        gload_lds16(bSrc[j] + (t) * 64, db + bDst[j]);                         \
  }
  O_STAGE(0, 0);
  O_STAGE(1, 1);
  int bR = 0, bS = 2;
  for (int t = 0; t < 12; ++t) {
    if (t < 11) {
      asm volatile("s_waitcnt vmcnt(6)" ::: "memory");
    } else {
      asm volatile("s_waitcnt vmcnt(0)" ::: "memory");
    }
    __builtin_amdgcn_s_barrier();
    __builtin_amdgcn_sched_barrier(0);
    if (t + 2 < 12) O_STAGE(bS, t + 2);
    const char* cur = smem + bR * PV_TSZ;
#pragma unroll
    for (int ks = 0; ks < 2; ++ks) {
      short8 af[4], bf[2];
#pragma unroll
      for (int mf = 0; mf < 4; ++mf)
        af[mf] = *(const short8*)(cur + aRowB[mf] + (((ks * 4 + q) ^ aSw[mf]) << 4));
#pragma unroll
      for (int nf = 0; nf < 2; ++nf)
        bf[nf] = *(const short8*)(cur + bRowB[nf] + (((ks * 4 + q) ^ bSw[nf]) << 4));
#pragma unroll
      for (int nf = 0; nf < 2; ++nf)
#pragma unroll
        for (int mf = 0; mf < 4; ++mf)
          acc[mf][nf] = __builtin_amdgcn_mfma_f32_16x16x32_bf16(af[mf], bf[nf],
                                                                acc[mf][nf], 0, 0, 0);
    }
    bR = (bR == 2) ? 0 : bR + 1;
    bS = (bS == 2) ? 0 : bS + 1;
  }
  float bo0 = bo[nBase + wvN * 32 + (lane & 15)];
  float bo1 = bo[nBase + wvN * 32 + 16 + (lane & 15)];
#pragma unroll
  for (int mf = 0; mf < 4; ++mf)
#pragma unroll
    for (int rr = 0; rr < 4; ++rr) {
      int row = mBase + wvM * 64 + mf * 16 + (lane >> 4) * 4 + rr;
      float z0 = acc[mf][0][rr] + bo0;
      float z1 = acc[mf][1][rr] + bo1;
      o[(size_t)row * DQ + nBase + wvN * 32 + (lane & 15)] = z0;
      o[(size_t)row * DQ + nBase + wvN * 32 + 16 + (lane & 15)] = z1;
      float s1 = z0 + z1, s2 = z0 * z0 + z1 * z1;
#pragma unroll
      for (int ofs = 1; ofs < 16; ofs <<= 1) {
        s1 += __shfl_xor(s1, ofs, 64);
        s2 += __shfl_xor(s2, ofs, 64);
      }
      if ((lane & 15) == 0) {
        atomicAdd(&oS12[row], s1);
        atomicAdd(&oS12[BN_ROWS + row], s2);
      }
    }
}

// K5: LayerNorm finalize + prompt broadcast -> out
__global__ __launch_bounds__(256) void k_out(const float* __restrict__ o,
                                             const float* __restrict__ oS12,
                                             const float* __restrict__ ln_g,
                                             const float* __restrict__ ln_b,
                                             const float* __restrict__ prompt,
                                             float* __restrict__ out) {
  const int row = blockIdx.x;
  const int tid = threadIdx.x;
  float mu = oS12[row] * (1.0f / DQ);
  float va = oS12[BN_ROWS + row] * (1.0f / DQ) - mu * mu;
  float rstd = rsqrtf(va + 1e-6f);
  int b = row >> 9, n = row & 511;
  size_t obase = ((size_t)b * (NXQ * (PQ + 1)) + (size_t)n * (PQ + 1)) * DQ;
#pragma unroll
  for (int j = 0; j < 3; ++j) {
    int col = tid + j * 256;
    out[obase + col] = (o[(size_t)row * DQ + col] - mu) * rstd * ln_g[col] + ln_b[col];
  }
#pragma unroll
  for (int pi = 0; pi < PQ; ++pi)
#pragma unroll
    for (int j = 0; j < 3; ++j) {
      int col = tid + j * 256;
      out[obase + (size_t)(1 + pi) * DQ + col] = prompt[pi * DQ + col];
    }
}

extern "C" void kernel_launch(void* const* d_in, const int* in_sizes, int n_in,
                              void* d_out, int out_size, void* d_ws, size_t ws_size,
                              hipStream_t stream) {
  (void)in_sizes; (void)n_in; (void)out_size; (void)ws_size;
  const float* x    = (const float*)d_in[0];
  const float* y    = (const float*)d_in[1];
  const float* Wx   = (const float*)d_in[2];
  const float* bx   = (const float*)d_in[3];
  const float* Wy   = (const float*)d_in[4];
  const float* by   = (const float*)d_in[5];
  const float* prom = (const float*)d_in[6];
  const float* Wq   = (const float*)d_in[7];
  const float* bq   = (const float*)d_in[8];
  const float* Wk   = (const float*)d_in[9];
  const float* bk   = (const float*)d_in[10];
  const float* Wv   = (const float*)d_in[11];
  const float* bv   = (const float*)d_in[12];
  const float* Wo   = (const float*)d_in[13];
  const float* bo   = (const float*)d_in[14];
  const float* lng  = (const float*)d_in[15];
  const float* lnb  = (const float*)d_in[16];
  float* out = (float*)d_out;
  char* ws = (char*)d_ws;

  // ---- workspace layout (aliased) ----
  size_t oWyT = 0;
  size_t oWvT = oWyT + (size_t)DQ * DYQ * 2;
  size_t oWoT = oWvT + (size_t)DQ * DQ * 2;
  size_t oXw  = oWoT + (size_t)DQ * DQ * 2;
  size_t oQ   = oXw + (size_t)BQ * DQ * 4 + 256;
  size_t oQK  = oQ + (size_t)BQ * DQ * 4;
  size_t oC   = oQK + (size_t)BQ * HQ * DQ * 4;
  size_t oRq  = oC + 1024;
  size_t oS   = oRq + (size_t)MY * 4;
  size_t oYbf = oS + (size_t)2 * BN_ROWS * 4;
  size_t oZ   = oYbf + (size_t)MY * DYQ * 2;
  size_t oP   = oYbf;                                 // alias (ybf dead)
  size_t oCtx = oYbf + (size_t)BN_ROWS * HQ * DQ * 2;
  size_t oO   = oZ;                                   // alias (z dead)

  ushort_t* WyT = (ushort_t*)(ws + oWyT);
  ushort_t* WvT = (ushort_t*)(ws + oWvT);
  ushort_t* WoT = (ushort_t*)(ws + oWoT);
  float* xw  = (float*)(ws + oXw);
  float* qv  = (float*)(ws + oQ);
  float* qk  = (float*)(ws + oQK);
  float* cQ  = (float*)(ws + oC);
  float* rowsq = (float*)(ws + oRq);
  float* oS12  = (float*)(ws + oS);
  ushort_t* ybf  = (ushort_t*)(ws + oYbf);
  ushort_t* zbuf = (ushort_t*)(ws + oZ);
  ushort_t* p    = (ushort_t*)(ws + oP);
  ushort_t* ctx  = (ushort_t*)(ws + oCtx);
  float* obuf    = (float*)(ws + oO);

  k_conv<<<dim3(4096), dim3(256), 0, stream>>>(y, Wy, Wv, Wo, ybf, WyT, WvT, WoT,
                                               rowsq, oS12, xw);
  k_q1<<<dim3(BQ, 6, 8), dim3(128), 0, stream>>>(x, Wx, bx, xw);
  k_q2<<<dim3(BQ, 6), dim3(128), 0, stream>>>(xw, Wq, bq, qv);
  k_q3<<<dim3(BQ * HQ), dim3(256), 0, stream>>>(Wk, bk, qv, qk, cQ);
  k_gemm_yp<<<dim3(1536), dim3(512), 0, stream>>>(ybf, WyT, by, zbuf, rowsq);
  k_attn<<<dim3(BN_ROWS), dim3(256), 0, stream>>>(zbuf, rowsq, qk, cQ, p);
  k_gemm_pv<<<dim3(BN_ROWS / 128, HQ), dim3(256), 0, stream>>>(p, WvT, bv, ctx);
  k_gemm_o<<<dim3(BN_ROWS / 128, DQ / 64), dim3(256), 0, stream>>>(ctx, WoT, bo, obuf, oS12);
  k_out<<<dim3(BN_ROWS), dim3(256), 0, stream>>>(obuf, oS12, lng, lnb, prom, out);
}